// Round 13
// baseline (32.329 us; speedup 1.0000x reference)
//
#include <hip/hip_runtime.h>
#include <hip/hip_bf16.h>

#define Bsz 2048
#define Dim 128
#define Nrows 4096

typedef float f32x4 __attribute__((ext_vector_type(4)));
typedef __bf16 bf16x8 __attribute__((ext_vector_type(8)));

// ws layout:
//   U     @ 0           : 4096*128*2 = 1 MiB (bf16 normalized rows)
//   part  @ 1 MiB       : 4096*32*4 = 512 KiB (per (row,strip32) sum exp(S-2), diag excl)
//   w1p   @ 2 MiB       : 128 KiB ; wallp @ +128K
//   w1    @ 2 MiB+256K  : 512 B ; wall @ +512 B ; c1 @ +1 KiB
//   rowC  @ 2 MiB+257K  : 1 KiB ; rowU @ +1 KiB

// K1: normalize [z; z_aug] -> bf16 U; per-block partials of w1/wall; block 0: c1
__global__ __launch_bounds__(256) void k_norm(const float* __restrict__ z,
                                              const float* __restrict__ za,
                                              const long long* __restrict__ labels,
                                              __bf16* __restrict__ U,
                                              float* __restrict__ w1p,
                                              float* __restrict__ wallp,
                                              int* __restrict__ c1out) {
    const int wid = threadIdx.x >> 6, lane = threadIdx.x & 63;
    __shared__ float s1[4][128];
    __shared__ float s0[4][128];
    float a1x = 0.f, a1y = 0.f, a0x = 0.f, a0y = 0.f;
    #pragma unroll
    for (int pass = 0; pass < 4; pass++) {
        const int r = blockIdx.x * 16 + pass * 4 + wid;
        const float* src = (r < Bsz) ? (z + (size_t)r * Dim) : (za + (size_t)(r - Bsz) * Dim);
        float2 x = reinterpret_cast<const float2*>(src)[lane];
        float ss = x.x * x.x + x.y * x.y;
        #pragma unroll
        for (int m = 1; m < 64; m <<= 1) ss += __shfl_xor(ss, m);
        const float sc = 1.0f / fmaxf(sqrtf(ss), 1e-12f);
        const float u0 = x.x * sc, u1 = x.y * sc;
        __bf16* dst = U + (size_t)r * Dim + 2 * lane;
        dst[0] = (__bf16)u0;
        dst[1] = (__bf16)u1;
        const float lf = (labels[r & (Bsz - 1)] == 1) ? 1.f : 0.f;
        a0x += u0; a0y += u1;
        a1x = fmaf(lf, u0, a1x); a1y = fmaf(lf, u1, a1y);
    }
    s1[wid][2 * lane] = a1x; s1[wid][2 * lane + 1] = a1y;
    s0[wid][2 * lane] = a0x; s0[wid][2 * lane + 1] = a0y;
    __syncthreads();
    const int t = threadIdx.x;
    if (t < 128) {
        w1p[blockIdx.x * 128 + t]   = s1[0][t] + s1[1][t] + s1[2][t] + s1[3][t];
        wallp[blockIdx.x * 128 + t] = s0[0][t] + s0[1][t] + s0[2][t] + s0[3][t];
    }
    if (blockIdx.x == 0) {
        __shared__ int ci[256];
        int c = 0;
        #pragma unroll
        for (int k = 0; k < 8; k++) c += (int)labels[t * 8 + k];
        ci[t] = c;
        __syncthreads();
        for (int s = 128; s > 0; s >>= 1) {
            if (t < s) ci[t] += ci[t + s];
            __syncthreads();
        }
        if (t == 0) c1out[0] = ci[0];
    }
}

// K2: 256x256 macro-tile Gram. Grid = 257 x 512 thr (8 waves, ~1 block/CU).
// Blocks 1..256: (ibk, jbk) 16x16. Stage i-panel + j-panel (256 rows x 256 B)
// into 128 KB static LDS (chunk-XOR swizzle; all loads issued before writes;
// ONE barrier). Wave (wiq=w&3, wjh=w>>2) = 64 i x 128 j; swapped operands:
// i = l15 lane-local -> scalar dsum[4]; j collapses in-register + 2 shuffles.
// Rank-1 epilogue (exp-sum only). Diag tile aliases Ai. Block 0: w-reduce.
__global__ __launch_bounds__(512, 2) void k_gram(const __bf16* __restrict__ U,
                                                 const float* __restrict__ w1p,
                                                 const float* __restrict__ wallp,
                                                 float* __restrict__ part,
                                                 float* __restrict__ w1,
                                                 float* __restrict__ wall) {
    if (blockIdx.x == 0) {   // side block: reduce 256 w-partials -> w1/wall
        const int t = threadIdx.x;
        if (t < 256) {
            const int d = t & 127;
            const float* src = (t < 128) ? w1p : wallp;
            float acc = 0.f;
            #pragma unroll 8
            for (int k = 0; k < 256; k++) acc += src[k * 128 + d];
            if (t < 128) w1[d] = acc; else wall[d] = acc;
        }
        return;
    }

    __shared__ __bf16 Ai[256 * 128];   // 64 KB: [row][16 chunks of 8 bf16]
    __shared__ __bf16 Aj[256 * 128];   // 64 KB

    const int ibk = (blockIdx.x - 1) >> 4, jbk = (blockIdx.x - 1) & 15;
    const bool diag = (ibk == jbk);
    const int ibase = ibk * 256, jbase = jbk * 256;
    const int w = threadIdx.x >> 6, lane = threadIdx.x & 63;
    const int wiq = w & 3, wjh = w >> 2;
    const int l15 = lane & 15, l4 = lane >> 4;

    // ---- stage: issue ALL global loads first, then LDS writes, one barrier
    {
        const int p = lane & 15, rsub = lane >> 4;
        bf16x8 sti[8], stj[8];
        #pragma unroll
        for (int it = 0; it < 8; it++) {
            const int rl = w * 32 + it * 4 + rsub;
            sti[it] = *reinterpret_cast<const bf16x8*>(U + (size_t)(ibase + rl) * Dim + p * 8);
        }
        if (!diag) {
            #pragma unroll
            for (int it = 0; it < 8; it++) {
                const int rl = w * 32 + it * 4 + rsub;
                stj[it] = *reinterpret_cast<const bf16x8*>(U + (size_t)(jbase + rl) * Dim + p * 8);
            }
        }
        #pragma unroll
        for (int it = 0; it < 8; it++) {
            const int rl = w * 32 + it * 4 + rsub;
            *reinterpret_cast<bf16x8*>(Ai + (rl * 16 + (p ^ (rl & 7))) * 8) = sti[it];
        }
        if (!diag) {
            #pragma unroll
            for (int it = 0; it < 8; it++) {
                const int rl = w * 32 + it * 4 + rsub;
                *reinterpret_cast<bf16x8*>(Aj + (rl * 16 + (p ^ (rl & 7))) * 8) = stj[it];
            }
        }
    }
    __syncthreads();
    const __bf16* AjP = diag ? Ai : Aj;

    // ---- i-side b-frags from LDS, resident (4 i-tiles x 4 ks)
    bf16x8 b[4][4];
    #pragma unroll
    for (int bt = 0; bt < 4; bt++)
        #pragma unroll
        for (int ks = 0; ks < 4; ks++) {
            const int row = wiq * 64 + bt * 16 + l15;
            b[bt][ks] = *reinterpret_cast<const bf16x8*>(
                Ai + (row * 16 + ((ks * 4 + l4) ^ (row & 7))) * 8);
        }

    float dsum[4] = {0.f, 0.f, 0.f, 0.f};
    const float KE1 = 2.8853900817779268f;    // 2*log2(e)
    const float KE0 = -2.8853900817779268f;

    #pragma unroll
    for (int at = 0; at < 8; at++) {
        const int arow = wjh * 128 + at * 16 + l15;
        bf16x8 a[4];
        #pragma unroll
        for (int ks = 0; ks < 4; ks++)
            a[ks] = *reinterpret_cast<const bf16x8*>(
                AjP + (arow * 16 + ((ks * 4 + l4) ^ (arow & 7))) * 8);
        const int jt = jbase + wjh * 128 + at * 16;

        #pragma unroll
        for (int bt = 0; bt < 4; bt++) {
            f32x4 acc = {0.f, 0.f, 0.f, 0.f};
            #pragma unroll
            for (int ks = 0; ks < 4; ks++)
                acc = __builtin_amdgcn_mfma_f32_16x16x32_bf16(a[ks], b[bt][ks], acc, 0, 0, 0);
            const bool dg = (jt == ibase + wiq * 64 + bt * 16);   // tile holds diagonal
            #pragma unroll
            for (int q = 0; q < 4; q++) {
                float e = exp2f(fmaf(acc[q], KE1, KE0));          // exp(S_ij - 2)
                if (dg && (l15 == l4 * 4 + q)) e = 0.f;           // exclude j == i
                dsum[bt] += e;
            }
        }
    }

    // ---- collapse the 4 l4-groups (j-partition); i = l15 stays lane-local
    const int strip = jbk * 2 + wjh;
    #pragma unroll
    for (int bt = 0; bt < 4; bt++) {
        float v0 = dsum[bt];
        v0 += __shfl_xor(v0, 16);
        v0 += __shfl_xor(v0, 32);
        if (l4 == 0)
            part[(ibase + wiq * 64 + bt * 16 + l15) * 32 + strip] = v0;
    }
}

// K3: 256 blocks x 256 thr; wave = 4 rows. 32-strip reduce (both halves read the
// same 32 -> butterfly yields 2x sum; fold the /2 into the log constant) + rank-1.
__global__ __launch_bounds__(256) void k_row(const __bf16* __restrict__ U,
                                             const long long* __restrict__ labels,
                                             const int* __restrict__ c1p,
                                             const float* __restrict__ part,
                                             const float* __restrict__ w1,
                                             const float* __restrict__ wall,
                                             float* __restrict__ rowC,
                                             float* __restrict__ rowU) {
    const int wid = threadIdx.x >> 6, lane = threadIdx.x & 63;
    const int ls = lane & 31;
    const int c1 = *c1p;
    const float w1a = w1[2 * lane], w1b = w1[2 * lane + 1];
    const float wa  = wall[2 * lane], wb = wall[2 * lane + 1];
    float cs = 0.f, us = 0.f;
    #pragma unroll
    for (int rr = 0; rr < 4; rr++) {
        const int i = blockIdx.x * 16 + wid * 4 + rr;
        const int partner = (i < Bsz) ? i + Bsz : i - Bsz;
        float dn = part[i * 32 + ls];             // halves duplicate -> 2x after reduce
        const float u0 = (float)U[(size_t)i * Dim + 2 * lane];
        const float u1 = (float)U[(size_t)i * Dim + 2 * lane + 1];
        const float p0 = (float)U[(size_t)partner * Dim + 2 * lane];
        const float p1 = (float)U[(size_t)partner * Dim + 2 * lane + 1];
        float d1 = u0 * w1a + u1 * w1b;   // u . w1
        float da = u0 * wa + u1 * wb;     // u . wall
        float ds = u0 * u0 + u1 * u1;     // u . u  (= S_ii / 2)
        float dp = u0 * p0 + u1 * p1;     // u . partner
        #pragma unroll
        for (int m = 1; m < 64; m <<= 1) {
            dn += __shfl_xor(dn, m);
            d1 += __shfl_xor(d1, m);
            da += __shfl_xor(da, m);
            ds += __shfl_xor(ds, m);
            dp += __shfl_xor(dp, m);
        }
        if (lane == 0) {
            const long long lb = labels[i & (Bsz - 1)];
            // dn is doubled: lnD = log(dn/2) + 2 = log(dn) + (2 - ln2)
            const float lnD = logf(dn) + 1.30685282f;
            const float uns = lnD - 2.0f * dp;            // pos = S(i, partner)
            const float cnt = 2.f * (float)((lb == 1) ? c1 : (Bsz - c1));
            const float sii = 2.f * ds;
            const float sumeq = ((lb == 1) ? 2.f * d1 : 2.f * (da - d1)) - sii;
            const float sup = lnD - sumeq / (cnt - 1.f);
            cs += (lb == 1) ? sup : uns;
            us += uns;
        }
    }
    __shared__ float wcs[4], wus[4];
    if (lane == 0) { wcs[wid] = cs; wus[wid] = us; }
    __syncthreads();
    if (threadIdx.x == 0) {
        rowC[blockIdx.x] = wcs[0] + wcs[1] + wcs[2] + wcs[3];
        rowU[blockIdx.x] = wus[0] + wus[1] + wus[2] + wus[3];
    }
}

// K4: combine 256 block results -> scalar loss
__global__ __launch_bounds__(256) void k_comb(const float* __restrict__ rowC,
                                              const float* __restrict__ rowU,
                                              const int* __restrict__ c1p,
                                              float* __restrict__ out) {
    __shared__ float sc[256], su[256];
    const int t = threadIdx.x;
    sc[t] = rowC[t];
    su[t] = rowU[t];
    __syncthreads();
    for (int s = 128; s > 0; s >>= 1) {
        if (t < s) { sc[t] += sc[t + s]; su[t] += su[t + s]; }
        __syncthreads();
    }
    if (t == 0) out[0] = ((*c1p > 0) ? sc[0] : su[0]) / (float)Nrows;
}

extern "C" void kernel_launch(void* const* d_in, const int* in_sizes, int n_in,
                              void* d_out, int out_size, void* d_ws, size_t ws_size,
                              hipStream_t stream) {
    const float* z  = (const float*)d_in[0];
    const float* za = (const float*)d_in[1];
    const long long* labels = (const long long*)d_in[2];

    char* ws = (char*)d_ws;
    __bf16* U     = (__bf16*)(ws);
    float*  part  = (float*)(ws + (1u << 20));
    float*  w1p   = (float*)(ws + (2u << 20));
    float*  wallp = (float*)(ws + (2u << 20) + (128u << 10));
    float*  w1    = (float*)(ws + (2u << 20) + (256u << 10));
    float*  wall  = (float*)(ws + (2u << 20) + (256u << 10) + 512);
    int*    c1    = (int*)  (ws + (2u << 20) + (256u << 10) + 1024);
    float*  rowC  = (float*)(ws + (2u << 20) + (257u << 10));
    float*  rowU  = (float*)(ws + (2u << 20) + (258u << 10));
    float*  out   = (float*)d_out;

    hipLaunchKernelGGL(k_norm, dim3(256), dim3(256), 0, stream, z, za, labels, U, w1p, wallp, c1);
    hipLaunchKernelGGL(k_gram, dim3(257), dim3(512), 0, stream, U, w1p, wallp, part, w1, wall);
    hipLaunchKernelGGL(k_row,  dim3(256), dim3(256), 0, stream, U, labels, c1, part, w1, wall, rowC, rowU);
    hipLaunchKernelGGL(k_comb, dim3(1),   dim3(256), 0, stream, rowC, rowU, c1, out);
}